// Round 7
// baseline (557.109 us; speedup 1.0000x reference)
//
#include <hip/hip_runtime.h>
#include <hip/hip_bf16.h>
#include <math.h>

#define B_  4
#define C_  64
#define H_  128
#define W_  128
#define HS  64
#define WS  64
#define L_  4096
#define E2  1024
#define KSPLIT 4
// extended pixel grid 66x66 (zero border = zero-pad semantics), padded to 35 tiles
#define GE  66
#define GR  4356        // 66*66 valid rows
#define GP  4480        // padded to 35*128
#define GT  35          // G tile grid

typedef _Float16 f16;
typedef f16 f16x2 __attribute__((ext_vector_type(2)));
typedef f16 f16x8 __attribute__((ext_vector_type(8)));
typedef float f32x4 __attribute__((ext_vector_type(4)));

__device__ __forceinline__ void gload16(const void* g, void* l) {
    __builtin_amdgcn_global_load_lds(
        (const __attribute__((address_space(1))) unsigned int*)g,
        (__attribute__((address_space(3))) unsigned int*)l, 16, 0, 0);
}

// ---------------- fused bilinear resize (128->64 align_corners) + transpose to
// Fext[b][r][c] f16 (r = (y+1)*66 + x+1; borders/tail pre-zeroed) + n2[r] = ||f_r||^2 ----------------
__global__ __launch_bounds__(256) void fbuild_kernel(const float* __restrict__ fg,
                                                     f16* __restrict__ Fext,
                                                     float* __restrict__ n2) {
    int y = blockIdx.x, b = blockIdx.y;
    int tid = threadIdx.x;
    __shared__ float T[64][65];
    const float sc = 127.0f / 63.0f;
    float yf = y * sc;
    int y0 = (int)floorf(yf); if (y0 > 127) y0 = 127;
    int y1 = min(y0 + 1, 127);
    float wy = yf - (float)y0;
    {
        int x = tid & 63;
        float xf = x * sc;
        int x0 = (int)floorf(xf); if (x0 > 127) x0 = 127;
        int x1 = min(x0 + 1, 127);
        float wx = xf - (float)x0;
        for (int cp = 0; cp < 16; ++cp) {
            int c = cp * 4 + (tid >> 6);
            const float* p = fg + (size_t)(b * 64 + c) * (128 * 128);
            float a = p[y0 * 128 + x0], bb = p[y0 * 128 + x1];
            float cc = p[y1 * 128 + x0], dd = p[y1 * 128 + x1];
            float t0 = a * (1.f - wy) + cc * wy;
            float t1 = bb * (1.f - wy) + dd * wy;
            T[c][x] = t0 * (1.f - wx) + t1 * wx;
        }
    }
    __syncthreads();
    int c = tid & 63, xi = tid >> 6;
    for (int j = 0; j < 16; ++j) {
        int x = xi + 4 * j;
        float v = T[c][x];
        int r = (y + 1) * GE + 1 + x;
        Fext[((size_t)b * GP + r) * 64 + c] = (f16)v;
        float s = v * v;
        #pragma unroll
        for (int off = 32; off; off >>= 1) s += __shfl_xor(s, off);
        if (c == 0) n2[b * GP + r] = s;
    }
}

// ---------------- nrm[p] = clamp(sqrt(3x3 boxsum of n2), 1e-4) + per-128-block min ----------------
__global__ __launch_bounds__(128) void norm_kernel(const float* __restrict__ n2,
                                                   float* __restrict__ nrm_all,
                                                   float* __restrict__ minN_all) {
    __shared__ float sm2[2];
    int t = threadIdx.x, pb = blockIdx.x, b = blockIdx.y;
    int p = pb * 128 + t;
    int pe = ((p >> 6) + 1) * GE + (p & 63) + 1;
    const float* n2b = n2 + (size_t)b * GP;
    float s = 0.f;
    #pragma unroll
    for (int dy = -1; dy <= 1; ++dy)
        #pragma unroll
        for (int dx = -1; dx <= 1; ++dx) s += n2b[pe + dy * GE + dx];
    float nv = fmaxf(sqrtf(s), 1e-4f);
    nrm_all[b * L_ + p] = nv;
    float mn = nv;
    #pragma unroll
    for (int off = 32; off; off >>= 1) mn = fminf(mn, __shfl_xor(mn, off));
    if ((t & 63) == 0) sm2[t >> 6] = mn;
    __syncthreads();
    if (t == 0) minN_all[b * 32 + pb] = fminf(sm2[0], sm2[1]);
}

// ---------------- VT[b][e][l] f16 : transposed 4x4xC background patches, batched ----------------
__global__ __launch_bounds__(256) void v_kernel(const float* __restrict__ bg,
                                                f16* __restrict__ VT_all) {
    int idx = blockIdx.x * 256 + threadIdx.x;
    int b = blockIdx.y;
    int l = idx & 4095, e = idx >> 12;
    int c = e >> 4, r = e & 15;
    int ky = r >> 2, kx = r & 3;
    int ly = l >> 6, lx = l & 63;
    int by = 2 * ly - 1 + ky, bx = 2 * lx - 1 + kx;
    float v = 0.f;
    if ((unsigned)by < 128u && (unsigned)bx < 128u)
        v = bg[((size_t)b * C_ + c) * (H_ * W_) + by * W_ + bx];
    VT_all[(size_t)b * E2 * L_ + idx] = (f16)v;
}

// ---------------- pixel Gram GEMM: G[r,c] = <F_r, F_c>, f16 out, + per-tile max Mc ----------------
// 128x128 tile, 4 waves, 16x16x32 f16 MFMA, K=64 (two BK-32 panels, m97 staging).
__global__ __launch_bounds__(256) void g_gemm(const f16* __restrict__ F,
                                              f16* __restrict__ G,
                                              float* __restrict__ Mc) {
    __shared__ __align__(16) f16 As0[128 * 32];
    __shared__ __align__(16) f16 As1[128 * 32];
    __shared__ __align__(16) f16 Bs0[128 * 32];
    __shared__ __align__(16) f16 Bs1[128 * 32];
    __shared__ float sred[4];
    const int bx = blockIdx.x, by = blockIdx.y;
    const int tid = threadIdx.x;
    const int w = tid >> 6, lane = tid & 63;
    const int row0 = by * 128, col0 = bx * 128;

    const int srow = w * 32 + (lane >> 2);
    const int scol = (lane & 3) * 8;
    const f16* gA = F + (size_t)(row0 + srow) * 64 + scol;
    const f16* gB = F + (size_t)(col0 + srow) * 64 + scol;
    const int l0 = (w * 32) * 32, l1 = (w * 32 + 16) * 32;

    gload16(gA,              As0 + l0);
    gload16(gA + 16 * 64,    As0 + l1);
    gload16(gA + 32,         As1 + l0);
    gload16(gA + 32 + 16 * 64, As1 + l1);
    gload16(gB,              Bs0 + l0);
    gload16(gB + 16 * 64,    Bs0 + l1);
    gload16(gB + 32,         Bs1 + l0);
    gload16(gB + 32 + 16 * 64, Bs1 + l1);

    const int wm = w >> 1, wn = w & 1;
    const int mfm = lane & 15, quad = lane >> 4;
    f32x4 acc[4][4] = {};
    __syncthreads();
    {
        f16x8 af[4], bf[4];
        #pragma unroll
        for (int mi = 0; mi < 4; ++mi)
            af[mi] = *(const f16x8*)&As0[(wm * 64 + mi * 16 + mfm) * 32 + quad * 8];
        #pragma unroll
        for (int ni = 0; ni < 4; ++ni)
            bf[ni] = *(const f16x8*)&Bs0[(wn * 64 + ni * 16 + mfm) * 32 + quad * 8];
        #pragma unroll
        for (int mi = 0; mi < 4; ++mi)
            #pragma unroll
            for (int ni = 0; ni < 4; ++ni)
                acc[mi][ni] = __builtin_amdgcn_mfma_f32_16x16x32_f16(
                    af[mi], bf[ni], acc[mi][ni], 0, 0, 0);
    }
    {
        f16x8 af[4], bf[4];
        #pragma unroll
        for (int mi = 0; mi < 4; ++mi)
            af[mi] = *(const f16x8*)&As1[(wm * 64 + mi * 16 + mfm) * 32 + quad * 8];
        #pragma unroll
        for (int ni = 0; ni < 4; ++ni)
            bf[ni] = *(const f16x8*)&Bs1[(wn * 64 + ni * 16 + mfm) * 32 + quad * 8];
        #pragma unroll
        for (int mi = 0; mi < 4; ++mi)
            #pragma unroll
            for (int ni = 0; ni < 4; ++ni)
                acc[mi][ni] = __builtin_amdgcn_mfma_f32_16x16x32_f16(
                    af[mi], bf[ni], acc[mi][ni], 0, 0, 0);
    }

    const int orow = row0 + wm * 64;
    const int ocol = col0 + wn * 64;
    float mx = -1e30f;
    #pragma unroll
    for (int mi = 0; mi < 4; ++mi)
        #pragma unroll
        for (int r = 0; r < 4; ++r) {
            int row = orow + mi * 16 + quad * 4 + r;
            #pragma unroll
            for (int ni = 0; ni < 4; ++ni) {
                float v = acc[mi][ni][r];
                mx = fmaxf(mx, v);
                G[(size_t)row * GP + ocol + ni * 16 + mfm] = (f16)v;
            }
        }
    #pragma unroll
    for (int off = 32; off; off >>= 1) mx = fmaxf(mx, __shfl_xor(mx, off));
    if (lane == 0) sred[w] = mx;
    __syncthreads();
    if (tid == 0)
        Mc[by * GT + bx] = fmaxf(fmaxf(sred[0], sred[1]), fmaxf(sred[2], sred[3]));
}

// ---------------- S assembly: S[p,l] = sum_{o in 3x3 diag} G[pe+o, le+o];
// tile skipped outright if 9*max(Mc region) bound says all-zero; else compute
// max logit, flag, and for nonzero tiles store E f16 + rowsum atomics. ----------------
__global__ __launch_bounds__(256) void assemble_kernel(const f16* __restrict__ G,
                                                       const float* __restrict__ nrm_b,
                                                       const float* __restrict__ minN_b,
                                                       const float* __restrict__ Mc,
                                                       f16* __restrict__ Eb,
                                                       float* __restrict__ rowsum_b,
                                                       int* __restrict__ flags) {
    const int lblk = blockIdx.x, pblk = blockIdx.y;
    const int tid = threadIdx.x;
    // rigorous tile bound: needed G rows [P0e-67, P0e+196], 9-term sum <= 9*regionmax
    {
        int P0e = 132 * pblk + 67, L0e = 132 * lblk + 67;
        int r0 = (P0e - 67) >> 7, r2 = min((P0e + 196) >> 7, GT - 1);
        int c0 = (L0e - 67) >> 7, c2 = min((L0e + 196) >> 7, GT - 1);
        float mx9 = -1e30f;
        for (int ri = r0; ri <= r2; ++ri)
            for (int ci = c0; ci <= c2; ++ci) mx9 = fmaxf(mx9, Mc[ri * GT + ci]);
        float lub = 90.0f * fmaxf(mx9, 0.f) / minN_b[lblk] - 10.0f * minN_b[pblk];
        if (lub < -17.0f) {
            if (tid == 0) flags[pblk * 32 + lblk] = 0;
            return;
        }
    }
    __shared__ float sm[4];
    const int g = tid >> 6, lane = tid & 63;
    const int L0 = lblk * 128;
    const int l_loc = lane * 2;
    const int lg0 = L0 + l_loc;                            // GLOBAL column index (round-6 bug: was local)
    const int le = ((lg0 >> 6) + 1) * GE + (lg0 & 63) + 1; // global extended column
    const float inl0 = 10.0f / nrm_b[lg0];
    const float inl1 = 10.0f / nrm_b[lg0 + 1];

    // phase A: tile max logit
    float mx = -1e30f;
    for (int i = 0; i < 32; ++i) {
        int p = pblk * 128 + g + 4 * i;
        int pe = ((p >> 6) + 1) * GE + (p & 63) + 1;
        const f16* base = G + (size_t)pe * GP + le;
        float s0 = 0.f, s1 = 0.f;
        #pragma unroll
        for (int dy = -1; dy <= 1; ++dy)
            #pragma unroll
            for (int dx = -1; dx <= 1; ++dx) {
                int o = dy * GE + dx;
                const f16* q = base + (ptrdiff_t)o * GP + o;
                s0 += (float)q[0]; s1 += (float)q[1];
            }
        float rp = 10.0f * nrm_b[p];
        mx = fmaxf(mx, fmaxf(s0 * inl0 - rp, s1 * inl1 - rp));
    }
    #pragma unroll
    for (int off = 32; off; off >>= 1) mx = fmaxf(mx, __shfl_xor(mx, off));
    if (lane == 0) sm[g] = mx;
    __syncthreads();
    float bmax = fmaxf(fmaxf(sm[0], sm[1]), fmaxf(sm[2], sm[3]));
    int nz = bmax > -17.5f;
    if (tid == 0) flags[pblk * 32 + lblk] = nz;
    if (!nz) return;

    // phase B: recompute, exp, store E, rowsum
    for (int i = 0; i < 32; ++i) {
        int p = pblk * 128 + g + 4 * i;
        int pe = ((p >> 6) + 1) * GE + (p & 63) + 1;
        const f16* base = G + (size_t)pe * GP + le;
        float s0 = 0.f, s1 = 0.f;
        #pragma unroll
        for (int dy = -1; dy <= 1; ++dy)
            #pragma unroll
            for (int dx = -1; dx <= 1; ++dx) {
                int o = dy * GE + dx;
                const f16* q = base + (ptrdiff_t)o * GP + o;
                s0 += (float)q[0]; s1 += (float)q[1];
            }
        float rp = 10.0f * nrm_b[p];
        float e0 = __expf(s0 * inl0 - rp);
        float e1 = __expf(s1 * inl1 - rp);
        f16x2 ev; ev.x = (f16)e0; ev.y = (f16)e1;
        *(f16x2*)&Eb[(size_t)p * L_ + L0 + l_loc] = ev;
        float v = e0 + e1;
        #pragma unroll
        for (int off = 32; off; off >>= 1) v += __shfl_xor(v, off);
        if (lane == 0) atomicAdd(&rowsum_b[p], v);
    }
}

// ---------------- PV MFMA GEMM: OPT_z[e,p] = sum_{l in slice z} VT[e,l]*E[p,l],
// f16 partials, skips zero E-tiles via flags (round-5 validated structure). ----------------
__global__ __launch_bounds__(256)
void pv_gemm(const f16* __restrict__ A, const f16* __restrict__ Bt,
             int kLen, f16* __restrict__ outp,
             const int* __restrict__ flags) {
    __shared__ __align__(16) f16 As0[128 * 32];
    __shared__ __align__(16) f16 As1[128 * 32];
    __shared__ __align__(16) f16 Bs0[128 * 32];
    __shared__ __align__(16) f16 Bs1[128 * 32];
    const int lin = blockIdx.x;
    const int by = lin & 7;
    const int i = lin >> 3;
    const int bx = i & 31, bz = i >> 5;

    const int tid = threadIdx.x;
    const int w = tid >> 6, lane = tid & 63;
    const int row0 = by * 128, col0 = bx * 128;
    const int k_start = bz * kLen;

    const int srow = w * 32 + (lane >> 2);
    const int scol = (lane & 3) * 8;
    const f16* gA = A + (size_t)(row0 + srow) * L_ + k_start + scol;
    const f16* gB = Bt + (size_t)(col0 + srow) * L_ + k_start + scol;
    const int l0 = (w * 32) * 32, l1 = (w * 32 + 16) * 32;

    const int wm = w >> 1, wn = w & 1;
    const int mfm = lane & 15, quad = lane >> 4;
    f32x4 acc[4][4] = {};

    for (int k0 = 0; k0 < kLen; k0 += 64) {
        if (!flags[(col0 >> 7) * 32 + ((k_start + k0) >> 7)]) continue;
        gload16(gA + k0,                    As0 + l0);
        gload16(gA + k0 + (size_t)16 * L_,  As0 + l1);
        gload16(gA + k0 + 32,               As1 + l0);
        gload16(gA + k0 + 32 + (size_t)16 * L_, As1 + l1);
        gload16(gB + k0,                    Bs0 + l0);
        gload16(gB + k0 + (size_t)16 * L_,  Bs0 + l1);
        gload16(gB + k0 + 32,               Bs1 + l0);
        gload16(gB + k0 + 32 + (size_t)16 * L_, Bs1 + l1);
        __syncthreads();
        {
            f16x8 af[4], bf[4];
            #pragma unroll
            for (int mi = 0; mi < 4; ++mi)
                af[mi] = *(const f16x8*)&As0[(wm * 64 + mi * 16 + mfm) * 32 + quad * 8];
            #pragma unroll
            for (int ni = 0; ni < 4; ++ni)
                bf[ni] = *(const f16x8*)&Bs0[(wn * 64 + ni * 16 + mfm) * 32 + quad * 8];
            #pragma unroll
            for (int mi = 0; mi < 4; ++mi)
                #pragma unroll
                for (int ni = 0; ni < 4; ++ni)
                    acc[mi][ni] = __builtin_amdgcn_mfma_f32_16x16x32_f16(
                        af[mi], bf[ni], acc[mi][ni], 0, 0, 0);
        }
        {
            f16x8 af[4], bf[4];
            #pragma unroll
            for (int mi = 0; mi < 4; ++mi)
                af[mi] = *(const f16x8*)&As1[(wm * 64 + mi * 16 + mfm) * 32 + quad * 8];
            #pragma unroll
            for (int ni = 0; ni < 4; ++ni)
                bf[ni] = *(const f16x8*)&Bs1[(wn * 64 + ni * 16 + mfm) * 32 + quad * 8];
            #pragma unroll
            for (int mi = 0; mi < 4; ++mi)
                #pragma unroll
                for (int ni = 0; ni < 4; ++ni)
                    acc[mi][ni] = __builtin_amdgcn_mfma_f32_16x16x32_f16(
                        af[mi], bf[ni], acc[mi][ni], 0, 0, 0);
        }
        __syncthreads();
    }

    const int orow = row0 + wm * 64;
    const int ocol = col0 + wn * 64;
    f16* Oo = outp + (size_t)bz * ((size_t)E2 * L_);
    #pragma unroll
    for (int mi = 0; mi < 4; ++mi) {
        #pragma unroll
        for (int r = 0; r < 4; ++r) {
            int row = orow + mi * 16 + quad * 4 + r;
            #pragma unroll
            for (int ni = 0; ni < 4; ++ni)
                Oo[(size_t)row * L_ + ocol + ni * 16 + mfm] = (f16)acc[mi][ni][r];
        }
    }
}

// ---------------- conv_transpose overlap-add gather on OPT[s][e][p] layout ----------------
__global__ __launch_bounds__(256) void gather_kernel(const f16* __restrict__ OPT,
                                                     const float* __restrict__ rowsum,
                                                     float* __restrict__ out_b) {
    int idx = blockIdx.x * 256 + threadIdx.x;
    if (idx >= C_ * H_ * W_) return;
    int X = idx & 127, Y = (idx >> 7) & 127, c = idx >> 14;
    int kyp = (Y + 1) & 1;
    int kxp = (X + 1) & 1;
    float sum = 0.f;
    #pragma unroll
    for (int ky = kyp; ky < 4; ky += 2) {
        int py = (Y + 1 - ky) >> 1;
        if ((unsigned)py >= 64u) continue;
        #pragma unroll
        for (int kx = kxp; kx < 4; kx += 2) {
            int px = (X + 1 - kx) >> 1;
            if ((unsigned)px >= 64u) continue;
            int p = py * 64 + px;
            int e = c * 16 + ky * 4 + kx;
            float v = 0.f;
            #pragma unroll
            for (int s = 0; s < KSPLIT; ++s)
                v += (float)OPT[((size_t)s * E2 + e) * L_ + p];
            sum += v * __builtin_amdgcn_rcpf(rowsum[p]);
        }
    }
    out_b[idx] = 0.25f * sum;
}

extern "C" void kernel_launch(void* const* d_in, const int* in_sizes, int n_in,
                              void* d_out, int out_size, void* d_ws, size_t ws_size,
                              hipStream_t stream) {
    const float* bg = (const float*)d_in[0];
    const float* fg = (const float*)d_in[1];
    float* out = (float*)d_out;
    char* w8 = (char*)d_ws;

    // workspace (bytes), total ~109.8 MB (< 114 MB proven in round 1).
    // OPT aliases G: G's lifetime (g_gemm..assemble) ends before PV writes OPT.
    f16*   Fext       = (f16*)  (w8);                 //  2,293,760  B x 4480 x 64
    float* n2         = (float*)(w8 + 2293760);       //     71,680  B x 4480
    float* nrm_all    = (float*)(w8 + 2365440);       //     65,536  B x 4096
    float* minN_all   = (float*)(w8 + 2430976);       //      4,096  B x 32
    float* rowsum_all = (float*)(w8 + 2435072);       //     65,536  B x 4096
    int*   flags      = (int*)  (w8 + 2500608);       //      4,096  32 x 32
    float* Mc         = (float*)(w8 + 2504704);       //      8,192  35 x 35
    f16*   VT_all     = (f16*)  (w8 + 2512896);       // 33,554,432  B x E2 x L
    f16*   G          = (f16*)  (w8 + 36067328);      // 40,140,800  4480 x 4480 (per-sample)
    f16*   OPT        = (f16*)  (w8 + 36067328);      // 33,554,432  aliases G
    f16*   Eb         = (f16*)  (w8 + 76208128);      // 33,554,432  (per-sample)

    hipMemsetAsync(Fext, 0, (size_t)B_ * GP * 64 * sizeof(f16), stream);
    hipMemsetAsync(n2, 0, (size_t)B_ * GP * sizeof(float), stream);
    hipMemsetAsync(rowsum_all, 0, (size_t)B_ * L_ * sizeof(float), stream);

    fbuild_kernel<<<dim3(64, B_), 256, 0, stream>>>(fg, Fext, n2);
    norm_kernel<<<dim3(32, B_), 128, 0, stream>>>(n2, nrm_all, minN_all);
    v_kernel<<<dim3((L_ * E2) / 256, B_), 256, 0, stream>>>(bg, VT_all);

    for (int b = 0; b < B_; ++b) {
        const f16* F_b     = Fext + (size_t)b * GP * 64;
        const float* nrm_b = nrm_all + (size_t)b * L_;
        const float* min_b = minN_all + (size_t)b * 32;
        float* rowsum_b    = rowsum_all + (size_t)b * L_;
        const f16* VT_b    = VT_all + (size_t)b * E2 * L_;
        float* out_b       = out + (size_t)b * C_ * H_ * W_;

        g_gemm<<<dim3(GT, GT), 256, 0, stream>>>(F_b, G, Mc);
        assemble_kernel<<<dim3(32, 32), 256, 0, stream>>>(
            G, nrm_b, min_b, Mc, Eb, rowsum_b, flags);
        pv_gemm<<<1024, 256, 0, stream>>>(VT_b, Eb, L_ / KSPLIT, OPT, flags);
        gather_kernel<<<(C_ * H_ * W_) / 256, 256, 0, stream>>>(OPT, rowsum_b, out_b);
    }
}